// Round 2
// baseline (1050.577 us; speedup 1.0000x reference)
//
#include <hip/hip_runtime.h>

// Blur (stylegan2 upfirdn2d, up=1, down=1, pad=(1,1)) on (4,128,513,513) f32.
// Output (4,128,512,512). Kernel is rank-1 -> separable 4-tap H + 4-tap V.
//
// v3: deeper software pipeline. v2 consumed each row's loads one sub-step
// after issue (~400 cy of cover at 4 waves/SIMD) vs ~900 cy HBM latency ->
// vmcnt-stall bound at ~2x the BW floor. Now a 6-row register window ring:
// row j issued at sub-step j-6, consumed at j-3 => ~1200 cy of cover.
// Ring-6 keeps VGPRs ~<=128 (4 waves/SIMD); ring-8 would tip to 3.
// Stores are nontemporal (output never re-read; keep L2/L3 for input halo).

#define W_IN  513
#define H_IN  513
#define W_OUT 512
#define H_OUT 512
#define IN_PLANE  (W_IN * H_IN)    // 263169
#define OUT_PLANE (W_OUT * H_OUT)  // 262144

typedef float f4 __attribute__((ext_vector_type(4)));
typedef float f2 __attribute__((ext_vector_type(2)));

// 4B-aligned wide loads (row stride 513 floats makes 16B alignment impossible;
// gfx950 allows dword-aligned dwordx4).
__device__ __forceinline__ f4 load4u(const float* p) {
    f4 v; __builtin_memcpy(&v, p, 16); return v;
}
__device__ __forceinline__ f2 load2u(const float* p) {
    f2 v; __builtin_memcpy(&v, p, 8); return v;
}

// One input row's 11-float window for 8 output cols: cols c-1 .. c+9. 11 VGPRs.
struct Win { f4 a, b; f2 c2; float m1; };

__global__ __launch_bounds__(256)
void blur_kernel(const float* __restrict__ in,
                 const float* __restrict__ kern,
                 float* __restrict__ out)
{
    const int t    = threadIdx.x;
    const int lane = t & 63;
    const int wv   = t >> 6;           // wave index in block: 4 row strips
    const int c    = lane << 3;        // output col base 0..504 (64 lanes cover 512)
    const int cm1  = (c == 0) ? 0 : (c - 1);   // clamped addr for col c-1
    const int y0   = (blockIdx.x * 4 + wv) * 32;
    const int p    = blockIdx.y;       // plane (n*c), 512 total

    const float* __restrict__ ip = in + (size_t)p * IN_PLANE;
    float* __restrict__ op = out + (size_t)p * OUT_PLANE + (size_t)y0 * W_OUT + c;

    // Separable factors (kern is rank-1). Reference flips kern.
    const float kx0 = kern[2 * 4 + 3];   // wf[1][0]
    const float kx1 = kern[2 * 4 + 2];   // wf[1][1]
    const float kx2 = kern[2 * 4 + 1];   // wf[1][2]
    const float kx3 = kern[2 * 4 + 0];   // wf[1][3]
    const float inv = 1.0f / kx1;
    const float a0  = kern[3 * 4 + 2] * inv;   // vertical taps, a1 == 1
    const float a2  = kern[1 * 4 + 2] * inv;
    const float a3  = kern[0 * 4 + 2] * inv;

    // Column pad masks (thread-invariant).
    const float mL = (c == 0)         ? 0.0f : 1.0f;   // masks W[0]  (col -1)
    const float mR = (c == W_OUT - 8) ? 0.0f : 1.0f;   // masks W[10] (col 513)

    // Issue loads for input row ri (address-clamped; validity folded at hcomp).
    auto ldrow = [&](int ri, Win& w) {
        const int riC = ri < 0 ? 0 : (ri > H_IN - 1 ? H_IN - 1 : ri);
        const float* rp = ip + (size_t)riC * W_IN;
        w.m1 = rp[cm1];              // col c-1
        w.a  = load4u(rp + c);       // cols c..c+3
        w.b  = load4u(rp + c + 4);   // cols c+4..c+7
        w.c2 = load2u(rp + c + 8);   // cols c+8,c+9
    };

    // Horizontal 4-tap. Pad rows -1/513 handled by zeroing the coefficients.
    auto hcomp = [&](int ri, const Win& w, float* h) {
        const float rv = (ri >= 0 && ri < H_IN) ? 1.0f : 0.0f;
        const float k0 = kx0 * rv, k1 = kx1 * rv, k2 = kx2 * rv, k3 = kx3 * rv;
        float W[11];
        W[0]  = w.m1 * mL;
        W[1]  = w.a.x; W[2] = w.a.y; W[3] = w.a.z; W[4] = w.a.w;
        W[5]  = w.b.x; W[6] = w.b.y; W[7] = w.b.z; W[8] = w.b.w;
        W[9]  = w.c2.x;
        W[10] = w.c2.y * mR;
#pragma unroll
        for (int k = 0; k < 8; ++k)
            h[k] = W[k] * k0 + W[k + 1] * k1 + W[k + 2] * k2 + W[k + 3] * k3;
    };

    // Vertical 4-tap (a1==1) + two nontemporal dwordx4 stores.
    auto vstore = [&](int r, const float* h0, const float* h1,
                      const float* h2, const float* h3) {
        float o[8];
#pragma unroll
        for (int k = 0; k < 8; ++k)
            o[k] = a0 * h0[k] + h1[k] + a2 * h2[k] + a3 * h3[k];
        f4 lo = (f4){o[0], o[1], o[2], o[3]};
        f4 hi = (f4){o[4], o[5], o[6], o[7]};
        __builtin_nontemporal_store(lo, reinterpret_cast<f4*>(op + (size_t)r * W_OUT));
        __builtin_nontemporal_store(hi, reinterpret_cast<f4*>(op + (size_t)r * W_OUT + 4));
    };

    // Window ring: slot s holds input row y0-1+j with j == s (mod 6).
    // Row j: issued at sub-step j-6, hcomp'd at sub-step j-3 (depth 3).
    Win Wn[6];
    float h[4][8];   // h history for input rows r-1..r+2 (slot = j & 3)

    // Prologue: 6 rows in flight (24 VMEM insts), then 3 h-rows.
#pragma unroll
    for (int j = 0; j < 6; ++j) ldrow(y0 - 1 + j, Wn[j]);
#pragma unroll
    for (int j = 0; j < 3; ++j) hcomp(y0 - 1 + j, Wn[j], h[j]);

    // Steady state (fully unrolled; all ring indices compile-time).
#pragma unroll
    for (int r = 0; r < 32; ++r) {
        if (r <= 28)                              // last needed row j=34 at r=28
            ldrow(y0 + 5 + r, Wn[r % 6]);         // row j=r+6 into freed slot
        hcomp(y0 + 2 + r, Wn[(r + 3) % 6], h[(r + 3) & 3]);
        vstore(r, h[r & 3], h[(r + 1) & 3], h[(r + 2) & 3], h[(r + 3) & 3]);
    }
}

extern "C" void kernel_launch(void* const* d_in, const int* in_sizes, int n_in,
                              void* d_out, int out_size, void* d_ws, size_t ws_size,
                              hipStream_t stream) {
    const float* x    = (const float*)d_in[0];  // (4,128,513,513) f32
    const float* kern = (const float*)d_in[1];  // (4,4) f32
    float* out        = (float*)d_out;          // (4,128,512,512) f32

    // Each block: 4 waves x (512 cols x 32 rows) = 512x128 of one plane.
    // Grid: 4 row-groups x 512 planes = 2048 blocks.
    dim3 grid(H_OUT / 128, 4 * 128, 1);
    dim3 block(256, 1, 1);
    blur_kernel<<<grid, block, 0, stream>>>(x, kern, out);
}